// Round 5
// baseline (244.536 us; speedup 1.0000x reference)
//
#include <hip/hip_runtime.h>
#include <cstdint>
#include <cstddef>

#define N_ROWS 2048
#define D_DIM  1024

typedef __bf16 bf16x8 __attribute__((ext_vector_type(8)));
typedef float  f32x4  __attribute__((ext_vector_type(4)));

__device__ __forceinline__ unsigned short f2bf(float f) {
    unsigned int u = __float_as_uint(f);
    unsigned int r = (u + 0x7fffu + ((u >> 16) & 1u)) >> 16;   // RNE
    return (unsigned short)r;
}
__device__ __forceinline__ float bf2f(unsigned short u) {
    return __uint_as_float(((unsigned int)u) << 16);
}
__device__ __forceinline__ void gload_lds16(const void* g, void* lds) {
    __builtin_amdgcn_global_load_lds(
        (const __attribute__((address_space(1))) unsigned int*)g,
        (__attribute__((address_space(3))) unsigned int*)lds, 16, 0, 0);
}

// ---------------------------------------------------------------------------
// dtype sniffing (targets int32/int64, mask bool/int/float) -> int32 buffers
// ---------------------------------------------------------------------------
__global__ __launch_bounds__(256) void preprocess_kernel(
    const unsigned char* __restrict__ traw,
    const unsigned char* __restrict__ mraw,
    int* __restrict__ tgt32, int* __restrict__ mask32)
{
    __shared__ int fFloat, fByte, fOdd;
    const int tid = threadIdx.x;
    if (tid == 0) { fFloat = 0; fByte = 0; fOdd = 0; }
    __syncthreads();

    const unsigned int* mw = (const unsigned int*)mraw;
    for (int i = tid; i < 512; i += 256) {
        unsigned int w = mw[i];
        if (w == 0x3f800000u) atomicOr(&fFloat, 1);
        if (w & 0xFFFFFF00u)  atomicOr(&fByte, 1);
    }
    const unsigned int* tw = (const unsigned int*)traw;
    for (int i = tid; i < N_ROWS; i += 256) {
        if ((i & 1) && tw[i] != 0u) atomicOr(&fOdd, 1);
    }
    __syncthreads();
    const int mlayout = fFloat ? 2 : (fByte ? 1 : 0);
    const int tis64   = fOdd ? 0 : 1;

    for (int i = tid; i < N_ROWS; i += 256) {
        long long t = tis64 ? ((const long long*)traw)[i] : (long long)((const int*)traw)[i];
        tgt32[i] = (int)t;
        int m;
        if (mlayout == 1) m = (mraw[i] != 0);
        else              m = (((const unsigned int*)mraw)[i] != 0u);
        mask32[i] = m;
    }
}

// ---------------------------------------------------------------------------
// gather + fp32->bf16: emb[n] = replace ? cls[b] : lhs[b,tok]
// ---------------------------------------------------------------------------
__global__ __launch_bounds__(256) void gather_cvt_kernel(
    const float* __restrict__ lhs, const float* __restrict__ cls,
    const int* __restrict__ bids, const int* __restrict__ toks,
    const int* __restrict__ mask32, unsigned short* __restrict__ emb)
{
    const int n = blockIdx.x;
    const int b = bids[n];
    const int tok = toks[n];
    const float* src = mask32[n] ? (cls + (size_t)b * D_DIM)
                                 : (lhs + ((size_t)b * 512 + (size_t)tok) * D_DIM);
    float4 v = ((const float4*)src)[threadIdx.x];
    ushort4 o;
    o.x = f2bf(v.x); o.y = f2bf(v.y); o.z = f2bf(v.z); o.w = f2bf(v.w);
    ((ushort4*)(emb + (size_t)n * D_DIM))[threadIdx.x] = o;
}

// ---------------------------------------------------------------------------
// single fused fp32->bf16 convert of all five weight tensors (vec4 grid-stride)
// ---------------------------------------------------------------------------
__global__ __launch_bounds__(256) void cvt_all_kernel(
    const float* __restrict__ s0, unsigned short* __restrict__ d0,  // headW  4002*1024
    const float* __restrict__ s1, unsigned short* __restrict__ d1,  // t0out 16000*256
    const float* __restrict__ s2, unsigned short* __restrict__ d2,  // t1out 30000*64
    const float* __restrict__ s3, unsigned short* __restrict__ d3,  // t0proj  256*1024
    const float* __restrict__ s4, unsigned short* __restrict__ d4)  // t1proj   64*1024
{
    const int total = 2610432;  // vec4 units
    for (int i = blockIdx.x * 256 + threadIdx.x; i < total; i += gridDim.x * 256) {
        const float* s; unsigned short* d; int off;
        if (i < 1024512)      { s = s0; d = d0; off = i; }
        else if (i < 2048512) { s = s1; d = d1; off = i - 1024512; }
        else if (i < 2528512) { s = s2; d = d2; off = i - 2048512; }
        else if (i < 2594048) { s = s3; d = d3; off = i - 2528512; }
        else                  { s = s4; d = d4; off = i - 2594048; }
        float4 v = ((const float4*)s)[off];
        ushort4 o;
        o.x = f2bf(v.x); o.y = f2bf(v.y); o.z = f2bf(v.z); o.w = f2bf(v.w);
        ((ushort4*)d)[off] = o;
    }
}

// sum 4 split-K partials, split h01 [2048][320] -> h0 bf16 [2048][256], h1 [2048][64]
__global__ __launch_bounds__(256) void cvt_h01_kernel(
    const float* __restrict__ h01p, unsigned short* __restrict__ h0,
    unsigned short* __restrict__ h1)
{
    const int idx = blockIdx.x * 256 + threadIdx.x;
    if (idx >= 2048 * 320) return;
    const float v = h01p[idx] + h01p[655360 + idx] + h01p[1310720 + idx]
                  + h01p[1966080 + idx];
    const int r = idx / 320;
    const int c = idx - r * 320;
    const unsigned short b = f2bf(v);
    if (c < 256) h0[r * 256 + c] = b;
    else         h1[r * 64 + (c - 256)] = b;
}

// ---------------------------------------------------------------------------
// shared pipelined 128x128 MFMA tile: acc = A[rowA0..+128][kBeg..+nt*32] @ W^T
// 2-phase double-buffered; stage(next) before compute(cur); one barrier/step.
// LDS XOR swizzle via pre-swizzled global source + linear LDS dest.
// ---------------------------------------------------------------------------
__device__ __forceinline__ void gemm_tile_pipeline(
    const unsigned short* __restrict__ A, int K,
    const unsigned short* __restrict__ W, int C,
    int rowA0, int cB, int kBeg, int nt,
    char* lds, int w, int l, f32x4 acc[4][4])
{
    const int sRl = (w << 5) + (l >> 2);
    const int sS  = l & 3;
    const unsigned short* aB[2];
    const unsigned short* wB[2];
    #pragma unroll
    for (int it = 0; it < 2; ++it) {
        const int R  = sRl + (it << 4);
        const int Sp = sS ^ ((R >> 1) & 3);
        aB[it] = A + (size_t)(rowA0 + R) * K + kBeg + Sp * 8;
        int Rw = cB + R; if (Rw >= C) Rw = C - 1;
        wB[it] = W + (size_t)Rw * K + kBeg + Sp * 8;
    }
    const int wrb = (w >> 1) << 6, wcb = (w & 1) << 6;
    const int q16 = l >> 4, r16 = l & 15;

    auto stage = [&](int kt, int buf) {
        char* Ab = lds + (buf << 13);
        char* Wb = lds + 16384 + (buf << 13);
        const int ko = kt << 5;
        #pragma unroll
        for (int it = 0; it < 2; ++it) {
            gload_lds16(aB[it] + ko, Ab + (w << 11) + (it << 10));
            gload_lds16(wB[it] + ko, Wb + (w << 11) + (it << 10));
        }
    };

    #pragma unroll
    for (int m = 0; m < 4; ++m)
        #pragma unroll
        for (int n = 0; n < 4; ++n) acc[m][n] = (f32x4){0.f, 0.f, 0.f, 0.f};

    stage(0, 0);
    __syncthreads();                         // implied vmcnt(0)

    for (int kt = 0; kt < nt; ++kt) {
        const int buf = kt & 1;
        if (kt + 1 < nt) stage(kt + 1, buf ^ 1);

        char* Ab = lds + (buf << 13);
        char* Wb = lds + 16384 + (buf << 13);
        bf16x8 af[4], bfr[4];
        #pragma unroll
        for (int m = 0; m < 4; ++m) {
            const int row = wrb + (m << 4) + r16;
            af[m] = *reinterpret_cast<const bf16x8*>(
                Ab + row * 64 + ((q16 ^ ((row >> 1) & 3)) << 4));
        }
        #pragma unroll
        for (int n = 0; n < 4; ++n) {
            const int row = wcb + (n << 4) + r16;
            bfr[n] = *reinterpret_cast<const bf16x8*>(
                Wb + row * 64 + ((q16 ^ ((row >> 1) & 3)) << 4));
        }
        #pragma unroll
        for (int m = 0; m < 4; ++m)
            #pragma unroll
            for (int n = 0; n < 4; ++n)
                acc[m][n] = __builtin_amdgcn_mfma_f32_16x16x32_bf16(
                    af[m], bfr[n], acc[m][n], 0, 0, 0);

        __syncthreads();                     // drains next-stage loads
    }
}

// ---------------------------------------------------------------------------
// proj GEMM (split-K, plain stores): h01 = emb @ projcat^T, grid (16,3,4)
// ---------------------------------------------------------------------------
__global__ __launch_bounds__(256) void gemm_proj_kernel(
    const unsigned short* __restrict__ A,
    const unsigned short* __restrict__ W,
    float* __restrict__ outF)
{
    __shared__ char lds[32768];
    const int gx = 16, gy = 3;
    const int nwg = 16 * 3 * 4;
    const int lid = blockIdx.x + gx * (blockIdx.y + gy * blockIdx.z);
    const int xcd = lid & 7, idx8 = lid >> 3;
    const int qq = nwg >> 3, rr = nwg & 7;
    const int wg = (xcd < rr ? xcd * (qq + 1) : rr * (qq + 1) + (xcd - rr) * qq) + idx8;
    const int bx = wg % gx;
    const int t1 = wg / gx;
    const int by = t1 % gy;
    const int bz = t1 / gy;

    const int tid = threadIdx.x;
    const int w = tid >> 6, l = tid & 63;
    const int rowA0 = bx << 7, cB = by << 7;

    f32x4 acc[4][4];
    gemm_tile_pipeline(A, 1024, W, 320, rowA0, cB, bz << 8, 8, lds, w, l, acc);

    const int wrb = (w >> 1) << 6, wcb = (w & 1) << 6;
    const int q16 = l >> 4, r16 = l & 15;
    float* o = outF + (size_t)bz * (N_ROWS * 320);
    #pragma unroll
    for (int n = 0; n < 4; ++n) {
        const int c = cB + wcb + (n << 4) + r16;
        if (c < 320) {
            #pragma unroll
            for (int m = 0; m < 4; ++m)
                #pragma unroll
                for (int r = 0; r < 4; ++r) {
                    const int row = rowA0 + wrb + (m << 4) + (q16 << 2) + r;
                    o[(size_t)row * 320 + c] = acc[m][n][r];
                }
        }
    }
}

// ---------------------------------------------------------------------------
// fused head+tail0+tail1 logits GEMM with sum-exp epilogue, grid (16, 392):
//   by <  32: head  (A=emb, K=1024, C=4002, bias)  -> pH[by]
//   by < 157: tail0 (A=h0,  K=256,  C=16000)       -> p0[by-32]
//   else    : tail1 (A=h1,  K=64,   C=30000)       -> p1[by-157]
// ---------------------------------------------------------------------------
__global__ __launch_bounds__(256) void gemm3_kernel(
    const unsigned short* __restrict__ emb,
    const unsigned short* __restrict__ headW, const float* __restrict__ headB,
    const unsigned short* __restrict__ h0, const unsigned short* __restrict__ t0W,
    const unsigned short* __restrict__ h1, const unsigned short* __restrict__ t1W,
    float* __restrict__ pH, float* __restrict__ p0, float* __restrict__ p1)
{
    __shared__ char lds[32768];
    const int nwg = 16 * 392;
    const int lid = blockIdx.x + (blockIdx.y << 4);
    const int xcd = lid & 7, idx8 = lid >> 3;
    const int qq = nwg >> 3, rr = nwg & 7;
    const int wg = (xcd < rr ? xcd * (qq + 1) : rr * (qq + 1) + (xcd - rr) * qq) + idx8;
    const int bx = wg & 15;
    const int by = wg >> 4;

    const unsigned short *A, *W;
    const float* bias = nullptr;
    float* part;
    int K, C, pIdx;
    if (by < 32)       { A = emb; K = 1024; W = headW; C = 4002;  bias = headB; part = pH; pIdx = by; }
    else if (by < 157) { A = h0;  K = 256;  W = t0W;   C = 16000; part = p0; pIdx = by - 32; }
    else               { A = h1;  K = 64;   W = t1W;   C = 30000; part = p1; pIdx = by - 157; }

    const int tid = threadIdx.x;
    const int w = tid >> 6, l = tid & 63;
    const int rowA0 = bx << 7, cB = pIdx << 7;

    f32x4 acc[4][4];
    gemm_tile_pipeline(A, K, W, C, rowA0, cB, 0, K >> 5, lds, w, l, acc);

    const int wrbit = w >> 1, wcbit = w & 1;
    const int q16 = l >> 4, r16 = l & 15;
    float bj[4]; bool vj[4];
    #pragma unroll
    for (int n = 0; n < 4; ++n) {
        const int c = cB + (wcbit << 6) + (n << 4) + r16;
        vj[n] = (c < C);
        bj[n] = (vj[n] && bias) ? bias[c] : 0.f;
    }
    float* pl = (float*)lds;   // pipeline finished: safe to reuse
    #pragma unroll
    for (int m = 0; m < 4; ++m)
        #pragma unroll
        for (int r = 0; r < 4; ++r) {
            float s = 0.f;
            #pragma unroll
            for (int n = 0; n < 4; ++n)
                if (vj[n]) s += __expf(acc[m][n][r] + bj[n]);
            s += __shfl_xor(s, 1); s += __shfl_xor(s, 2);
            s += __shfl_xor(s, 4); s += __shfl_xor(s, 8);
            if (r16 == 0)
                pl[(wcbit << 7) + (wrbit << 6) + (m << 4) + (q16 << 2) + r] = s;
        }
    __syncthreads();
    if (tid < 128)
        part[(size_t)pIdx * N_ROWS + rowA0 + tid] = pl[tid] + pl[128 + tid];
}

// ---------------------------------------------------------------------------
// parallel partial reduce: grid (64, 3); block = 32 rows x 8 partial-groups
// ---------------------------------------------------------------------------
__global__ __launch_bounds__(256) void reduce_partials_kernel(
    const float* __restrict__ pH, const float* __restrict__ p0,
    const float* __restrict__ p1,
    float* __restrict__ seH, float* __restrict__ se0, float* __restrict__ se1)
{
    const int tid = threadIdx.x;
    const int r32 = tid & 31, g = tid >> 5;
    const int row = blockIdx.x * 32 + r32;
    const float* p; float* o; int P;
    if (blockIdx.y == 0)      { p = pH; o = seH; P = 32;  }
    else if (blockIdx.y == 1) { p = p0; o = se0; P = 125; }
    else                      { p = p1; o = se1; P = 235; }
    float s = 0.f;
    for (int i = g; i < P; i += 8) s += p[(size_t)i * N_ROWS + row];
    __shared__ float pl[8][32];
    pl[g][r32] = s;
    __syncthreads();
    if (tid < 32) {
        float v = 0.f;
        #pragma unroll
        for (int i = 0; i < 8; ++i) v += pl[i][tid];
        o[blockIdx.x * 32 + tid] = v;
    }
}

// ---------------------------------------------------------------------------
// per-row target / cluster logit dots (one wave per row)
// ---------------------------------------------------------------------------
__global__ __launch_bounds__(256) void dot_kernel(
    const unsigned short* __restrict__ emb,
    const unsigned short* __restrict__ headW,
    const float* __restrict__ headB,
    const unsigned short* __restrict__ h0,
    const unsigned short* __restrict__ t0out,
    const unsigned short* __restrict__ h1,
    const unsigned short* __restrict__ t1out,
    const int* __restrict__ tgt32,
    float* __restrict__ tgtH, float* __restrict__ c0, float* __restrict__ c1,
    float* __restrict__ tg0, float* __restrict__ tg1)
{
    const int n = blockIdx.x * 4 + (threadIdx.x >> 6);
    const int l = threadIdx.x & 63;
    const int t = tgt32[n];

    const unsigned short* e  = emb + (size_t)n * 1024;
    const int hrow = (t < 4000) ? t : 0;
    const unsigned short* wt = headW + (size_t)hrow * 1024;
    const unsigned short* w0 = headW + (size_t)4000 * 1024;
    const unsigned short* w1 = headW + (size_t)4001 * 1024;

    float st = 0.f, s0 = 0.f, s1 = 0.f;
    for (int i = l; i < 1024; i += 64) {
        const float ev = bf2f(e[i]);
        st += ev * bf2f(wt[i]);
        s0 += ev * bf2f(w0[i]);
        s1 += ev * bf2f(w1[i]);
    }
    float stail = 0.f;
    if (t >= 4000 && t < 20000) {
        const unsigned short* h  = h0 + (size_t)n * 256;
        const unsigned short* ww = t0out + (size_t)(t - 4000) * 256;
        for (int i = l; i < 256; i += 64) stail += bf2f(h[i]) * bf2f(ww[i]);
    } else if (t >= 20000) {
        const unsigned short* h  = h1 + (size_t)n * 64;
        const unsigned short* ww = t1out + (size_t)(t - 20000) * 64;
        stail = bf2f(h[l]) * bf2f(ww[l]);
    }
    #pragma unroll
    for (int msk = 1; msk < 64; msk <<= 1) {
        st    += __shfl_xor(st, msk);
        s0    += __shfl_xor(s0, msk);
        s1    += __shfl_xor(s1, msk);
        stail += __shfl_xor(stail, msk);
    }
    if (l == 0) {
        c0[n] = s0 + headB[4000];
        c1[n] = s1 + headB[4001];
        if (t < 4000)       tgtH[n] = st + headB[t];
        else if (t < 20000) tg0[n]  = stail;
        else                tg1[n]  = stail;
    }
}

// ---------------------------------------------------------------------------
__global__ __launch_bounds__(256) void finalize_kernel(
    const float* __restrict__ seH, const float* __restrict__ se0,
    const float* __restrict__ se1,
    const float* __restrict__ tgtH, const float* __restrict__ tg0,
    const float* __restrict__ tg1,
    const float* __restrict__ c0, const float* __restrict__ c1,
    const int* __restrict__ tgt32,
    float* __restrict__ out)
{
    const int tid = threadIdx.x;
    float lsum = 0.f;
    for (int n = tid; n < N_ROWS; n += 256) {
        const float lseH = logf(seH[n]);
        const int t = tgt32[n];
        float o;
        if (t < 4000)        o = tgtH[n] - lseH;
        else if (t < 20000)  o = (c0[n] - lseH) + tg0[n] - logf(se0[n]);
        else                 o = (c1[n] - lseH) + tg1[n] - logf(se1[n]);
        out[n] = o;
        lsum += o;
    }
    #pragma unroll
    for (int m = 1; m < 64; m <<= 1) lsum += __shfl_xor(lsum, m);
    __shared__ float wsum[4];
    const int wid = tid >> 6;
    if ((tid & 63) == 0) wsum[wid] = lsum;
    __syncthreads();
    if (tid == 0) out[N_ROWS] = -(wsum[0] + wsum[1] + wsum[2] + wsum[3]) / (float)N_ROWS;
}

// ---------------------------------------------------------------------------
extern "C" void kernel_launch(void* const* d_in, const int* in_sizes, int n_in,
                              void* d_out, int out_size, void* d_ws, size_t ws_size,
                              hipStream_t stream)
{
    const unsigned char* traw = (const unsigned char*)d_in[0];
    const float* lhs    = (const float*)d_in[1];
    const float* cls    = (const float*)d_in[2];
    const int*   bids   = (const int*)d_in[3];
    const int*   toks   = (const int*)d_in[4];
    const unsigned char* mraw = (const unsigned char*)d_in[5];
    const float* headW  = (const float*)d_in[6];
    const float* headB  = (const float*)d_in[7];
    const float* t0proj = (const float*)d_in[8];
    const float* t0out  = (const float*)d_in[9];
    const float* t1proj = (const float*)d_in[10];
    const float* t1out  = (const float*)d_in[11];

    char* ws = (char*)d_ws;
    unsigned short* emb_bf   = (unsigned short*)(ws + 0);          //  4,194,304
    unsigned short* headW_bf = (unsigned short*)(ws + 4194304);    //  8,196,096
    unsigned short* t0out_bf = (unsigned short*)(ws + 12390400);   //  8,192,000
    unsigned short* t1out_bf = (unsigned short*)(ws + 20582400);   //  3,840,000
    unsigned short* projcat  = (unsigned short*)(ws + 24422400);   //    655,360
    float*          h01p     = (float*)(ws + 25077760);            // 10,485,760 (4 slices)
    unsigned short* h0_bf    = (unsigned short*)(ws + 35563520);   //  1,048,576
    unsigned short* h1_bf    = (unsigned short*)(ws + 36612096);   //    262,144
    int*   tgt32  = (int*)(ws + 36874240);
    int*   mask32 = (int*)(ws + 36882432);
    float* seH_p  = (float*)(ws + 36890624);   //  32*2048*4 =   262,144
    float* se0_p  = (float*)(ws + 37152768);   // 125*2048*4 = 1,024,000
    float* se1_p  = (float*)(ws + 38176768);   // 235*2048*4 = 1,925,120
    float* seH    = (float*)(ws + 40101888);
    float* se0    = (float*)(ws + 40110080);
    float* se1    = (float*)(ws + 40118272);
    float* tgtH   = (float*)(ws + 40126464);
    float* c0     = (float*)(ws + 40134656);
    float* c1     = (float*)(ws + 40142848);
    float* tg0    = (float*)(ws + 40151040);
    float* tg1    = (float*)(ws + 40159232);

    preprocess_kernel<<<1, 256, 0, stream>>>(traw, mraw, tgt32, mask32);
    gather_cvt_kernel<<<N_ROWS, 256, 0, stream>>>(lhs, cls, bids, toks, mask32, emb_bf);

    cvt_all_kernel<<<2048, 256, 0, stream>>>(headW, headW_bf, t0out, t0out_bf,
                                             t1out, t1out_bf, t0proj, projcat,
                                             t1proj, projcat + 262144);

    // proj GEMM: h01 = emb @ [t0proj;t1proj]^T  (C=320, split-K z=4 x 256)
    gemm_proj_kernel<<<dim3(16, 3, 4), 256, 0, stream>>>(emb_bf, projcat, h01p);
    cvt_h01_kernel<<<2560, 256, 0, stream>>>(h01p, h0_bf, h1_bf);

    // fused head + tail0 + tail1 logits with sum-exp epilogue
    gemm3_kernel<<<dim3(16, 392), 256, 0, stream>>>(
        emb_bf, headW_bf, headB, h0_bf, t0out_bf, h1_bf, t1out_bf,
        seH_p, se0_p, se1_p);

    reduce_partials_kernel<<<dim3(64, 3), 256, 0, stream>>>(
        seH_p, se0_p, se1_p, seH, se0, se1);

    dot_kernel<<<512, 256, 0, stream>>>(emb_bf, headW_bf, headB, h0_bf, t0out_bf,
                                        h1_bf, t1out_bf, tgt32,
                                        tgtH, c0, c1, tg0, tg1);
    finalize_kernel<<<1, 256, 0, stream>>>(seH, se0, se1, tgtH, tg0, tg1,
                                           c0, c1, tgt32, (float*)d_out);
}